// Round 9
// baseline (125.202 us; speedup 1.0000x reference)
//
#include <hip/hip_runtime.h>
#include <hip/hip_bf16.h>

// Problem constants (from reference)
#define BATCH 512
#define NKER  256
#define LEN   1000      // embedding input length
#define EDIM  3
#define OUTN  128
#define NROWS (BATCH * NKER)      // 131072
#define NPAIRS (NROWS / 2)        // 65536
#define NF4   (LEN / 4)           // 250 float4 per row
#define FC_IN (EDIM * NKER)       // 768
#define PREC  48                  // floats per pair record: [8 groups][6 vals]

typedef float fv4 __attribute__((ext_vector_type(4)));

#define DOT4(a, w) ((a)[0]*(w)[0] + (a)[1]*(w)[1] + (a)[2]*(w)[2] + (a)[3]*(w)[3])

// ---------------- Stage 1: partial y ----------------------------------------
// Round-7 proven structure (pair of rows per iter, W in LDS, NT loads, all 8
// loads up front), EXCEPT the butterfly stops after masks {1,2,4}: each
// 8-lane group holds partials of all 6 values; lanes l&7==0 store their
// group's 6 floats to ypart[pair][group][val]. The expensive cross-group
// shuffles (masks 8,16,32 = DS-pipe ds_swizzle/bpermute) are eliminated;
// stage 2 folds the 8 group-partials (cheap LDS adds).
__global__ __launch_bounds__(256) void stage1_emb(const float* __restrict__ x,
                                                  const float* __restrict__ W_emb,
                                                  float* __restrict__ ypart) {
    __shared__ float w_s[EDIM][LEN];   // 12 KB
    for (int i = threadIdx.x; i < EDIM * LEN; i += 256) {
        w_s[i / LEN][i % LEN] = W_emb[i];
    }
    __syncthreads();

    const int wave = threadIdx.x >> 6;
    const int lane = threadIdx.x & 63;
    const int gw = blockIdx.x * 4 + wave;           // global wave id, 0..8191

    const bool tail = (lane < NF4 - 192);           // lane < 58 has a 4th slice
    const int f3 = tail ? (lane + 192) : 0;         // clamped LDS index (x zeroed)
    const fv4 z4 = {0.f, 0.f, 0.f, 0.f};

    const fv4* w0p = reinterpret_cast<const fv4*>(&w_s[0][0]);
    const fv4* w1p = reinterpret_cast<const fv4*>(&w_s[1][0]);
    const fv4* w2p = reinterpret_cast<const fv4*>(&w_s[2][0]);

    #pragma unroll 1
    for (int i = 0; i < 8; ++i) {
        const int rowA = gw * 2 + i * 16384;        // pairs strided across array
        const fv4* xa = reinterpret_cast<const fv4*>(x + (size_t)rowA * LEN);
        const fv4* xb = reinterpret_cast<const fv4*>(x + (size_t)(rowA + 1) * LEN);

        // Issue all 8 loads before any use (8 KB contiguous in flight per wave)
        fv4 a0 = __builtin_nontemporal_load(&xa[lane]);
        fv4 a1 = __builtin_nontemporal_load(&xa[lane + 64]);
        fv4 a2 = __builtin_nontemporal_load(&xa[lane + 128]);
        fv4 a3 = tail ? __builtin_nontemporal_load(&xa[lane + 192]) : z4;
        fv4 b0 = __builtin_nontemporal_load(&xb[lane]);
        fv4 b1 = __builtin_nontemporal_load(&xb[lane + 64]);
        fv4 b2 = __builtin_nontemporal_load(&xb[lane + 128]);
        fv4 b3 = tail ? __builtin_nontemporal_load(&xb[lane + 192]) : z4;

        float sA0, sA1, sA2, sB0, sB1, sB2;
        {
            fv4 w;
            // chunk 0 (W read once, used for both rows)
            w = w0p[lane];       sA0  = DOT4(a0, w);  sB0  = DOT4(b0, w);
            w = w1p[lane];       sA1  = DOT4(a0, w);  sB1  = DOT4(b0, w);
            w = w2p[lane];       sA2  = DOT4(a0, w);  sB2  = DOT4(b0, w);
            // chunk 1
            w = w0p[lane + 64];  sA0 += DOT4(a1, w);  sB0 += DOT4(b1, w);
            w = w1p[lane + 64];  sA1 += DOT4(a1, w);  sB1 += DOT4(b1, w);
            w = w2p[lane + 64];  sA2 += DOT4(a1, w);  sB2 += DOT4(b1, w);
            // chunk 2
            w = w0p[lane + 128]; sA0 += DOT4(a2, w);  sB0 += DOT4(b2, w);
            w = w1p[lane + 128]; sA1 += DOT4(a2, w);  sB1 += DOT4(b2, w);
            w = w2p[lane + 128]; sA2 += DOT4(a2, w);  sB2 += DOT4(b2, w);
            // chunk 3 (tail; x zeroed for lanes >= 58, W index clamped)
            w = w0p[f3];         sA0 += DOT4(a3, w);  sB0 += DOT4(b3, w);
            w = w1p[f3];         sA1 += DOT4(a3, w);  sB1 += DOT4(b3, w);
            w = w2p[f3];         sA2 += DOT4(a3, w);  sB2 += DOT4(b3, w);
        }

        // Partial butterfly: masks {1,2,4} only (intra-8-group, 6 parallel
        // chains). Cross-group stages (8,16,32) are deferred to stage 2.
        #pragma unroll
        for (int m = 1; m <= 4; m <<= 1) {
            sA0 += __shfl_xor(sA0, m);
            sA1 += __shfl_xor(sA1, m);
            sA2 += __shfl_xor(sA2, m);
            sB0 += __shfl_xor(sB0, m);
            sB1 += __shfl_xor(sB1, m);
            sB2 += __shfl_xor(sB2, m);
        }
        if ((lane & 7) == 0) {
            float* pr = ypart + (size_t)(rowA >> 1) * PREC + (lane >> 3) * 6;
            pr[0] = sA0;
            pr[1] = sA1;
            pr[2] = sA2;
            pr[3] = sB0;
            pr[4] = sB1;
            pr[5] = sB2;
        }
    }
}

// ---------------- Stage 1.5: transpose W_fc2 [OUT, 768] -> Wt [768, OUT] ----
__global__ __launch_bounds__(256) void transpose_wfc2(const float* __restrict__ W,
                                                      float* __restrict__ Wt) {
    int idx = blockIdx.x * 256 + threadIdx.x;   // index into Wt (coalesced write)
    if (idx < FC_IN * OUTN) {
        int j = idx >> 7;          // 0..767
        int o = idx & (OUTN - 1);  // 0..127
        Wt[idx] = W[o * FC_IN + j];
    }
}

// ---------------- Stage 2: fold partials, then out = ys @ Wt + bias ---------
// 512 blocks x 256 threads (proven round-3/7 shape; L2-latency/TLP-bound).
// Prologue: stage the block's [128 pairs][8][6] = 24 KB tile coalesced into
// LDS, fold 8 group-partials per j into ys[768]. j-loop unchanged.
__global__ __launch_bounds__(256) void stage2_fc(const float* __restrict__ ypart,
                                                 const float* __restrict__ Wt,
                                                 const float* __restrict__ bias,
                                                 float* __restrict__ out) {
    __shared__ float tile[128 * PREC];   // 24 KB
    __shared__ float ys[FC_IN];          // 3 KB
    __shared__ float part[OUTN];         // 0.5 KB
    const int b = blockIdx.x;

    // Coalesced tile load: 1536 float4 by 256 threads
    const fv4* src = reinterpret_cast<const fv4*>(ypart + (size_t)b * 128 * PREC);
    fv4* dst = reinterpret_cast<fv4*>(tile);
    for (int i = threadIdx.x; i < 128 * PREC / 4; i += 256) dst[i] = src[i];
    __syncthreads();

    // Fold: ys[j] = sum over 8 groups; j -> (k = j/3, e = j%3), record
    // row (k>>1), value slot (k&1)*3 + e, group stride 6.
    for (int j = threadIdx.x; j < FC_IN; j += 256) {
        const int k = j / 3;
        const int e = j - k * 3;
        const float* tp = &tile[(k >> 1) * PREC + (k & 1) * 3 + e];
        ys[j] = ((tp[0] + tp[6]) + (tp[12] + tp[18])) +
                ((tp[24] + tp[30]) + (tp[36] + tp[42]));
    }
    __syncthreads();

    const int o = threadIdx.x & (OUTN - 1);
    const int h = threadIdx.x >> 7;               // 0 or 1
    const int j0 = h * (FC_IN / 2);
    float acc = 0.f;
    #pragma unroll 8
    for (int j = j0; j < j0 + FC_IN / 2; ++j) {
        acc += ys[j] * Wt[j * OUTN + o];   // ys[j] broadcast; Wt coalesced across lanes
    }
    if (h) part[o] = acc;
    __syncthreads();
    if (!h) out[(size_t)b * OUTN + o] = acc + part[o] + bias[o];
}

extern "C" void kernel_launch(void* const* d_in, const int* in_sizes, int n_in,
                              void* d_out, int out_size, void* d_ws, size_t ws_size,
                              hipStream_t stream) {
    const float* x     = (const float*)d_in[0];   // [512, 256, 1000]
    const float* W_emb = (const float*)d_in[1];   // [3, 1000]
    const float* W_fc2 = (const float*)d_in[2];   // [128, 768]
    const float* b_fc2 = (const float*)d_in[3];   // [128]
    float* out = (float*)d_out;                   // [512, 128]

    // Workspace layout: ypart [65536*48] floats (12.6 MB), then Wt [768*128]
    float* ypart = (float*)d_ws;
    float* Wt = ypart + (size_t)NPAIRS * PREC;

    // Transpose fc2 weight first (independent of stage 1)
    transpose_wfc2<<<(FC_IN * OUTN + 255) / 256, 256, 0, stream>>>(W_fc2, Wt);

    // Stage 1: 2048 blocks x 256 threads; each wave does 8 strided row-pairs
    stage1_emb<<<2048, 256, 0, stream>>>(x, W_emb, ypart);

    // Stage 2: one block per batch row, 256 threads (o x j-half)
    stage2_fc<<<BATCH, 256, 0, stream>>>(ypart, Wt, b_fc2, out);
}

// Round 10
// 108.954 us; speedup vs baseline: 1.1491x; 1.1491x over previous
//
#include <hip/hip_runtime.h>
#include <hip/hip_bf16.h>

// Problem constants (from reference)
#define BATCH 512
#define NKER  256
#define LEN   1000      // embedding input length
#define EDIM  3
#define OUTN  128
#define NROWS (BATCH * NKER)      // 131072
#define NF4   (LEN / 4)           // 250 float4 per row
#define FC_IN (EDIM * NKER)       // 768

typedef float fv4 __attribute__((ext_vector_type(4)));

#define DOT4(a, w) ((a)[0]*(w)[0] + (a)[1]*(w)[1] + (a)[2]*(w)[2] + (a)[3]*(w)[3])

// ---------------- Stage 1: y[b,k,e] = sum_l x[b,k,l] * W_emb[e,l] ----------
// Round-7 proven core (pair of rows/iter, W in LDS read once per pair, NT
// loads, full 6-chain butterfly, strided pairs) + next-pair load issue moved
// BETWEEN the DOT4s (which consume the load registers) and the butterfly, so
// the reduce runs with 8 loads in flight (WAR-only reuse: no extra live set).
// NO launch-bounds min-waves cap (round-4 lesson: cap -> 32 VGPR -> spill).
__global__ __launch_bounds__(256) void stage1_emb(const float* __restrict__ x,
                                                  const float* __restrict__ W_emb,
                                                  float* __restrict__ y) {
    __shared__ float w_s[EDIM][LEN];   // 12 KB
    for (int i = threadIdx.x; i < EDIM * LEN; i += 256) {
        w_s[i / LEN][i % LEN] = W_emb[i];
    }
    __syncthreads();

    const int wave = threadIdx.x >> 6;
    const int lane = threadIdx.x & 63;
    const int gw = blockIdx.x * 4 + wave;           // global wave id, 0..8191

    const bool tail = (lane < NF4 - 192);           // lane < 58 has a 4th slice
    const int f3 = tail ? (lane + 192) : 0;         // clamped LDS index (x zeroed)
    const fv4 z4 = {0.f, 0.f, 0.f, 0.f};

    const fv4* w0p = reinterpret_cast<const fv4*>(&w_s[0][0]);
    const fv4* w1p = reinterpret_cast<const fv4*>(&w_s[1][0]);
    const fv4* w2p = reinterpret_cast<const fv4*>(&w_s[2][0]);

    // Prime: first pair's loads
    fv4 a0, a1, a2, a3, b0, b1, b2, b3;
    {
        const fv4* xa = reinterpret_cast<const fv4*>(x + (size_t)(gw * 2) * LEN);
        const fv4* xb = reinterpret_cast<const fv4*>(x + (size_t)(gw * 2 + 1) * LEN);
        a0 = __builtin_nontemporal_load(&xa[lane]);
        a1 = __builtin_nontemporal_load(&xa[lane + 64]);
        a2 = __builtin_nontemporal_load(&xa[lane + 128]);
        a3 = tail ? __builtin_nontemporal_load(&xa[lane + 192]) : z4;
        b0 = __builtin_nontemporal_load(&xb[lane]);
        b1 = __builtin_nontemporal_load(&xb[lane + 64]);
        b2 = __builtin_nontemporal_load(&xb[lane + 128]);
        b3 = tail ? __builtin_nontemporal_load(&xb[lane + 192]) : z4;
    }

    #pragma unroll 1
    for (int i = 0; i < 8; ++i) {
        const int rowA = gw * 2 + i * 16384;        // pairs strided across array

        float sA0, sA1, sA2, sB0, sB1, sB2;
        {
            fv4 w;
            // chunk 0 (W read once, used for both rows)
            w = w0p[lane];       sA0  = DOT4(a0, w);  sB0  = DOT4(b0, w);
            w = w1p[lane];       sA1  = DOT4(a0, w);  sB1  = DOT4(b0, w);
            w = w2p[lane];       sA2  = DOT4(a0, w);  sB2  = DOT4(b0, w);
            // chunk 1
            w = w0p[lane + 64];  sA0 += DOT4(a1, w);  sB0 += DOT4(b1, w);
            w = w1p[lane + 64];  sA1 += DOT4(a1, w);  sB1 += DOT4(b1, w);
            w = w2p[lane + 64];  sA2 += DOT4(a1, w);  sB2 += DOT4(b1, w);
            // chunk 2
            w = w0p[lane + 128]; sA0 += DOT4(a2, w);  sB0 += DOT4(b2, w);
            w = w1p[lane + 128]; sA1 += DOT4(a2, w);  sB1 += DOT4(b2, w);
            w = w2p[lane + 128]; sA2 += DOT4(a2, w);  sB2 += DOT4(b2, w);
            // chunk 3 (tail; x zeroed for lanes >= 58, W index clamped)
            w = w0p[f3];         sA0 += DOT4(a3, w);  sB0 += DOT4(b3, w);
            w = w1p[f3];         sA1 += DOT4(a3, w);  sB1 += DOT4(b3, w);
            w = w2p[f3];         sA2 += DOT4(a3, w);  sB2 += DOT4(b3, w);
        }

        // Issue next pair's loads NOW (registers just went dead -> WAR reuse,
        // no added live set). The butterfly below runs with 8 loads in flight.
        if (i + 1 < 8) {    // uniform (scalar) branch
            const int rowN = gw * 2 + (i + 1) * 16384;
            const fv4* xa = reinterpret_cast<const fv4*>(x + (size_t)rowN * LEN);
            const fv4* xb = reinterpret_cast<const fv4*>(x + (size_t)(rowN + 1) * LEN);
            a0 = __builtin_nontemporal_load(&xa[lane]);
            a1 = __builtin_nontemporal_load(&xa[lane + 64]);
            a2 = __builtin_nontemporal_load(&xa[lane + 128]);
            a3 = tail ? __builtin_nontemporal_load(&xa[lane + 192]) : z4;
            b0 = __builtin_nontemporal_load(&xb[lane]);
            b1 = __builtin_nontemporal_load(&xb[lane + 64]);
            b2 = __builtin_nontemporal_load(&xb[lane + 128]);
            b3 = tail ? __builtin_nontemporal_load(&xb[lane + 192]) : z4;
        }
        __builtin_amdgcn_sched_barrier(0);   // pin load issue above the reduce

        // Full 64-lane butterfly reduction: 6 independent chains (ILP)
        #pragma unroll
        for (int m = 32; m >= 1; m >>= 1) {
            sA0 += __shfl_xor(sA0, m);
            sA1 += __shfl_xor(sA1, m);
            sA2 += __shfl_xor(sA2, m);
            sB0 += __shfl_xor(sB0, m);
            sB1 += __shfl_xor(sB1, m);
            sB2 += __shfl_xor(sB2, m);
        }
        if (lane == 0) {
            float* yr = y + (size_t)rowA * EDIM;   // rows A,B contiguous: 24 B
            yr[0] = sA0;
            yr[1] = sA1;
            yr[2] = sA2;
            yr[3] = sB0;
            yr[4] = sB1;
            yr[5] = sB2;
        }
    }
}

// ---------------- Stage 1.5: transpose W_fc2 [OUT, 768] -> Wt [768, OUT] ----
__global__ __launch_bounds__(256) void transpose_wfc2(const float* __restrict__ W,
                                                      float* __restrict__ Wt) {
    int idx = blockIdx.x * 256 + threadIdx.x;   // index into Wt (coalesced write)
    if (idx < FC_IN * OUTN) {
        int j = idx >> 7;          // 0..767
        int o = idx & (OUTN - 1);  // 0..127
        Wt[idx] = W[o * FC_IN + j];
    }
}

// ---------------- Stage 2: out[b,o] = sum_j y[b,j] * Wt[j,o] + bias[o] ------
// Round-3/7 proven version: 512 blocks x 256 threads (128 o x 2 j-halves).
// Stage 2 is L2-latency-bound, not Wt-traffic-bound: max blocks = max TLP.
__global__ __launch_bounds__(256) void stage2_fc(const float* __restrict__ y,
                                                 const float* __restrict__ Wt,
                                                 const float* __restrict__ bias,
                                                 float* __restrict__ out) {
    __shared__ float ys[FC_IN];
    __shared__ float part[OUTN];
    const int b = blockIdx.x;
    for (int i = threadIdx.x; i < FC_IN; i += 256) ys[i] = y[(size_t)b * FC_IN + i];
    __syncthreads();

    const int o = threadIdx.x & (OUTN - 1);
    const int h = threadIdx.x >> 7;               // 0 or 1
    const int j0 = h * (FC_IN / 2);
    float acc = 0.f;
    #pragma unroll 8
    for (int j = j0; j < j0 + FC_IN / 2; ++j) {
        acc += ys[j] * Wt[j * OUTN + o];   // ys[j] broadcast; Wt coalesced across lanes
    }
    if (h) part[o] = acc;
    __syncthreads();
    if (!h) out[(size_t)b * OUTN + o] = acc + part[o] + bias[o];
}

extern "C" void kernel_launch(void* const* d_in, const int* in_sizes, int n_in,
                              void* d_out, int out_size, void* d_ws, size_t ws_size,
                              hipStream_t stream) {
    const float* x     = (const float*)d_in[0];   // [512, 256, 1000]
    const float* W_emb = (const float*)d_in[1];   // [3, 1000]
    const float* W_fc2 = (const float*)d_in[2];   // [128, 768]
    const float* b_fc2 = (const float*)d_in[3];   // [128]
    float* out = (float*)d_out;                   // [512, 128]

    // Workspace layout: y [131072*3] floats, then Wt [768*128] floats
    float* y  = (float*)d_ws;
    float* Wt = y + (size_t)NROWS * EDIM;

    // Transpose fc2 weight first (independent of stage 1)
    transpose_wfc2<<<(FC_IN * OUTN + 255) / 256, 256, 0, stream>>>(W_fc2, Wt);

    // Stage 1: 2048 blocks x 256 threads; each wave does 8 strided row-pairs
    stage1_emb<<<2048, 256, 0, stream>>>(x, W_emb, y);

    // Stage 2: one block per batch row, 256 threads (o x j-half)
    stage2_fc<<<BATCH, 256, 0, stream>>>(y, Wt, b_fc2, out);
}

// Round 11
// 102.600 us; speedup vs baseline: 1.2203x; 1.0619x over previous
//
#include <hip/hip_runtime.h>
#include <hip/hip_bf16.h>

// Problem constants (from reference)
#define BATCH 512
#define NKER  256
#define LEN   1000      // embedding input length
#define EDIM  3
#define OUTN  128
#define NROWS (BATCH * NKER)      // 131072
#define NF4   (LEN / 4)           // 250 float4 per row
#define FC_IN (EDIM * NKER)       // 768

typedef float fv4 __attribute__((ext_vector_type(4)));

#define DOT4(a, w) ((a)[0]*(w)[0] + (a)[1]*(w)[1] + (a)[2]*(w)[2] + (a)[3]*(w)[3])

// ---------------- Stage 1: y[b,k,e] = sum_l x[b,k,l] * W_emb[e,l] ----------
// Round-9 proven version (best: 109.0 us): pair of rows/iter, W in LDS read
// once per pair, NT loads, next-pair loads issued between DOT4s and the
// butterfly (WAR register reuse), full 6-chain butterfly, strided pairs,
// no launch-bounds min-waves cap.
__global__ __launch_bounds__(256) void stage1_emb(const float* __restrict__ x,
                                                  const float* __restrict__ W_emb,
                                                  float* __restrict__ y) {
    __shared__ float w_s[EDIM][LEN];   // 12 KB
    for (int i = threadIdx.x; i < EDIM * LEN; i += 256) {
        w_s[i / LEN][i % LEN] = W_emb[i];
    }
    __syncthreads();

    const int wave = threadIdx.x >> 6;
    const int lane = threadIdx.x & 63;
    const int gw = blockIdx.x * 4 + wave;           // global wave id, 0..8191

    const bool tail = (lane < NF4 - 192);           // lane < 58 has a 4th slice
    const int f3 = tail ? (lane + 192) : 0;         // clamped LDS index (x zeroed)
    const fv4 z4 = {0.f, 0.f, 0.f, 0.f};

    const fv4* w0p = reinterpret_cast<const fv4*>(&w_s[0][0]);
    const fv4* w1p = reinterpret_cast<const fv4*>(&w_s[1][0]);
    const fv4* w2p = reinterpret_cast<const fv4*>(&w_s[2][0]);

    // Prime: first pair's loads
    fv4 a0, a1, a2, a3, b0, b1, b2, b3;
    {
        const fv4* xa = reinterpret_cast<const fv4*>(x + (size_t)(gw * 2) * LEN);
        const fv4* xb = reinterpret_cast<const fv4*>(x + (size_t)(gw * 2 + 1) * LEN);
        a0 = __builtin_nontemporal_load(&xa[lane]);
        a1 = __builtin_nontemporal_load(&xa[lane + 64]);
        a2 = __builtin_nontemporal_load(&xa[lane + 128]);
        a3 = tail ? __builtin_nontemporal_load(&xa[lane + 192]) : z4;
        b0 = __builtin_nontemporal_load(&xb[lane]);
        b1 = __builtin_nontemporal_load(&xb[lane + 64]);
        b2 = __builtin_nontemporal_load(&xb[lane + 128]);
        b3 = tail ? __builtin_nontemporal_load(&xb[lane + 192]) : z4;
    }

    #pragma unroll 1
    for (int i = 0; i < 8; ++i) {
        const int rowA = gw * 2 + i * 16384;        // pairs strided across array

        float sA0, sA1, sA2, sB0, sB1, sB2;
        {
            fv4 w;
            // chunk 0 (W read once, used for both rows)
            w = w0p[lane];       sA0  = DOT4(a0, w);  sB0  = DOT4(b0, w);
            w = w1p[lane];       sA1  = DOT4(a0, w);  sB1  = DOT4(b0, w);
            w = w2p[lane];       sA2  = DOT4(a0, w);  sB2  = DOT4(b0, w);
            // chunk 1
            w = w0p[lane + 64];  sA0 += DOT4(a1, w);  sB0 += DOT4(b1, w);
            w = w1p[lane + 64];  sA1 += DOT4(a1, w);  sB1 += DOT4(b1, w);
            w = w2p[lane + 64];  sA2 += DOT4(a1, w);  sB2 += DOT4(b1, w);
            // chunk 2
            w = w0p[lane + 128]; sA0 += DOT4(a2, w);  sB0 += DOT4(b2, w);
            w = w1p[lane + 128]; sA1 += DOT4(a2, w);  sB1 += DOT4(b2, w);
            w = w2p[lane + 128]; sA2 += DOT4(a2, w);  sB2 += DOT4(b2, w);
            // chunk 3 (tail; x zeroed for lanes >= 58, W index clamped)
            w = w0p[f3];         sA0 += DOT4(a3, w);  sB0 += DOT4(b3, w);
            w = w1p[f3];         sA1 += DOT4(a3, w);  sB1 += DOT4(b3, w);
            w = w2p[f3];         sA2 += DOT4(a3, w);  sB2 += DOT4(b3, w);
        }

        // Issue next pair's loads NOW (registers just went dead -> WAR reuse,
        // no added live set). The butterfly below runs with 8 loads in flight.
        if (i + 1 < 8) {    // uniform (scalar) branch
            const int rowN = gw * 2 + (i + 1) * 16384;
            const fv4* xa = reinterpret_cast<const fv4*>(x + (size_t)rowN * LEN);
            const fv4* xb = reinterpret_cast<const fv4*>(x + (size_t)(rowN + 1) * LEN);
            a0 = __builtin_nontemporal_load(&xa[lane]);
            a1 = __builtin_nontemporal_load(&xa[lane + 64]);
            a2 = __builtin_nontemporal_load(&xa[lane + 128]);
            a3 = tail ? __builtin_nontemporal_load(&xa[lane + 192]) : z4;
            b0 = __builtin_nontemporal_load(&xb[lane]);
            b1 = __builtin_nontemporal_load(&xb[lane + 64]);
            b2 = __builtin_nontemporal_load(&xb[lane + 128]);
            b3 = tail ? __builtin_nontemporal_load(&xb[lane + 192]) : z4;
        }
        __builtin_amdgcn_sched_barrier(0);   // pin load issue above the reduce

        // Full 64-lane butterfly reduction: 6 independent chains (ILP)
        #pragma unroll
        for (int m = 32; m >= 1; m >>= 1) {
            sA0 += __shfl_xor(sA0, m);
            sA1 += __shfl_xor(sA1, m);
            sA2 += __shfl_xor(sA2, m);
            sB0 += __shfl_xor(sB0, m);
            sB1 += __shfl_xor(sB1, m);
            sB2 += __shfl_xor(sB2, m);
        }
        if (lane == 0) {
            float* yr = y + (size_t)rowA * EDIM;   // rows A,B contiguous: 24 B
            yr[0] = sA0;
            yr[1] = sA1;
            yr[2] = sA2;
            yr[3] = sB0;
            yr[4] = sB1;
            yr[5] = sB2;
        }
    }
}

// ---------------- Stage 1.5: transpose W_fc2 [OUT, 768] -> Wt [768, OUT] ----
__global__ __launch_bounds__(256) void transpose_wfc2(const float* __restrict__ W,
                                                      float* __restrict__ Wt) {
    int idx = blockIdx.x * 256 + threadIdx.x;   // index into Wt (coalesced write)
    if (idx < FC_IN * OUTN) {
        int j = idx >> 7;          // 0..767
        int o = idx & (OUTN - 1);  // 0..127
        Wt[idx] = W[o * FC_IN + j];
    }
}

// ---------------- Stage 2: out[b,o] = sum_j y[b,j] * Wt[j,o] + bias[o] ------
// 512 blocks x 512 threads: thread = (o, j-quarter). Serial j-chain cut to
// 192 iterations (was 384); 8 waves/block for L2-latency hiding; tree-combine
// the 4 partials in LDS. (Proven direction: rounds 1/5 showed fewer blocks
// hurt; round 3 showed halving the chain helped.)
__global__ __launch_bounds__(512) void stage2_fc(const float* __restrict__ y,
                                                 const float* __restrict__ Wt,
                                                 const float* __restrict__ bias,
                                                 float* __restrict__ out) {
    __shared__ float ys[FC_IN];          // 3 KB
    __shared__ float part[3][OUTN];      // 1.5 KB
    const int b = blockIdx.x;

    const fv4* ysrc = reinterpret_cast<const fv4*>(y + (size_t)b * FC_IN);
    fv4* ydst = reinterpret_cast<fv4*>(&ys[0]);
    for (int i = threadIdx.x; i < FC_IN / 4; i += 512) ydst[i] = ysrc[i];
    __syncthreads();

    const int o = threadIdx.x & (OUTN - 1);
    const int q = threadIdx.x >> 7;               // 0..3 (j-quarter)
    const int j0 = q * (FC_IN / 4);
    float acc = 0.f;
    #pragma unroll 8
    for (int j = j0; j < j0 + FC_IN / 4; ++j) {
        acc += ys[j] * Wt[j * OUTN + o];   // ys[j] broadcast; Wt coalesced across lanes
    }
    if (q) part[q - 1][o] = acc;
    __syncthreads();
    if (!q) {
        out[(size_t)b * OUTN + o] = acc + part[0][o] + part[1][o] + part[2][o] + bias[o];
    }
}

extern "C" void kernel_launch(void* const* d_in, const int* in_sizes, int n_in,
                              void* d_out, int out_size, void* d_ws, size_t ws_size,
                              hipStream_t stream) {
    const float* x     = (const float*)d_in[0];   // [512, 256, 1000]
    const float* W_emb = (const float*)d_in[1];   // [3, 1000]
    const float* W_fc2 = (const float*)d_in[2];   // [128, 768]
    const float* b_fc2 = (const float*)d_in[3];   // [128]
    float* out = (float*)d_out;                   // [512, 128]

    // Workspace layout: y [131072*3] floats, then Wt [768*128] floats
    float* y  = (float*)d_ws;
    float* Wt = y + (size_t)NROWS * EDIM;

    // Transpose fc2 weight first (independent of stage 1)
    transpose_wfc2<<<(FC_IN * OUTN + 255) / 256, 256, 0, stream>>>(W_fc2, Wt);

    // Stage 1: 2048 blocks x 256 threads; each wave does 8 strided row-pairs
    stage1_emb<<<2048, 256, 0, stream>>>(x, W_emb, y);

    // Stage 2: one block per batch row, 512 threads (o x j-quarter)
    stage2_fc<<<BATCH, 512, 0, stream>>>(y, Wt, b_fc2, out);
}